// Round 7
// baseline (490.199 us; speedup 1.0000x reference)
//
#include <hip/hip_runtime.h>

#define DD 48
#define TT 512
#define RS 100   // bp row stride: A cols 0..47, B cols 48..95, dump 96..99
#define PF 4     // emit ring depth == unroll

// Value via fmax chain; index via cmp/select off the value path.
// First-index wins ties: strict (r > l) to move right at every node. (Proven R6.)
__device__ __forceinline__ void tree_argmax48(const float* s, float& best, int& idx) {
  float v1[24]; int x1[24];
#pragma unroll
  for (int k = 0; k < 24; ++k) {
    float l = s[2 * k], r = s[2 * k + 1];
    v1[k] = fmaxf(l, r);
    x1[k] = (r > l) ? 2 * k + 1 : 2 * k;
  }
  float v2[12]; int x2[12];
#pragma unroll
  for (int k = 0; k < 12; ++k) {
    float l = v1[2 * k], r = v1[2 * k + 1];
    v2[k] = fmaxf(l, r);
    x2[k] = (r > l) ? x1[2 * k + 1] : x1[2 * k];
  }
  float v3[6]; int x3[6];
#pragma unroll
  for (int k = 0; k < 6; ++k) {
    float l = v2[2 * k], r = v2[2 * k + 1];
    v3[k] = fmaxf(l, r);
    x3[k] = (r > l) ? x2[2 * k + 1] : x2[2 * k];
  }
  float v4[3]; int x4[3];
#pragma unroll
  for (int k = 0; k < 3; ++k) {
    float l = v3[2 * k], r = v3[2 * k + 1];
    v4[k] = fmaxf(l, r);
    x4[k] = (r > l) ? x3[2 * k + 1] : x3[2 * k];
  }
  float vm = fmaxf(v4[0], v4[1]);
  int xm = (v4[1] > v4[0]) ? x4[1] : x4[0];
  best = fmaxf(vm, v4[2]);
  idx = (v4[2] > vm) ? x4[2] : xm;
}

__global__ __launch_bounds__(64, 1) void crf_viterbi(const float* __restrict__ logits,
                                                     const int* __restrict__ lens,
                                                     const float* __restrict__ trans,
                                                     int* __restrict__ out) {
  const int blk = blockIdx.x;
  const int j = threadIdx.x;
  const int jj = j < DD ? j : DD - 1;

  __shared__ unsigned char bp[TT * RS];      // 50 KB, rows 1..Lmax-1 used
  __shared__ __align__(16) float albcA[64];
  __shared__ __align__(16) float albcB[64];

  float tcol[DD];
#pragma unroll
  for (int i = 0; i < DD; ++i) tcol[i] = trans[i * DD + jj];

  const float* lgA = logits + (size_t)(2 * blk) * TT * DD;
  const float* lgB = logits + (size_t)(2 * blk + 1) * TT * DD;
  const int LA = lens[2 * blk];
  const int LB = lens[2 * blk + 1];
  const int Lmax = LA > LB ? LA : LB;

  float alphaA = lgA[jj];
  float alphaB = lgB[jj];
  albcA[j] = alphaA;
  albcB[j] = alphaB;

  const int colA = (j < DD) ? j : 96;        // dump cols for lanes 48..63
  const int colB = (j < DD) ? DD + j : 98;

  float eA[PF], eB[PF];
#pragma unroll
  for (int k = 0; k < PF; ++k) {
    eA[k] = lgA[(1 + k) * DD + jj];
    eB[k] = lgB[(1 + k) * DD + jj];
  }

  for (int tb = 1; tb < Lmax; tb += PF) {
#pragma unroll
    for (int u = 0; u < PF; ++u) {
      const int t = tb + u;
      // issue both broadcast read sets (wave-uniform addrs -> conflict-free)
      float4 ra[12], rb[12];
      const float4* apA = (const float4*)albcA;
      const float4* apB = (const float4*)albcB;
#pragma unroll
      for (int q = 0; q < 12; ++q) ra[q] = apA[q];
#pragma unroll
      for (int q = 0; q < 12; ++q) rb[q] = apB[q];
      // A chain
      float sA[DD];
#pragma unroll
      for (int q = 0; q < 12; ++q) {
        sA[4 * q + 0] = ra[q].x + tcol[4 * q + 0];
        sA[4 * q + 1] = ra[q].y + tcol[4 * q + 1];
        sA[4 * q + 2] = ra[q].z + tcol[4 * q + 2];
        sA[4 * q + 3] = ra[q].w + tcol[4 * q + 3];
      }
      float bestA; int idxA;
      tree_argmax48(sA, bestA, idxA);
      alphaA = (t < LA) ? (bestA + eA[u]) : alphaA;  // branchless freeze
      // B chain
      float sB[DD];
#pragma unroll
      for (int q = 0; q < 12; ++q) {
        sB[4 * q + 0] = rb[q].x + tcol[4 * q + 0];
        sB[4 * q + 1] = rb[q].y + tcol[4 * q + 1];
        sB[4 * q + 2] = rb[q].z + tcol[4 * q + 2];
        sB[4 * q + 3] = rb[q].w + tcol[4 * q + 3];
      }
      float bestB; int idxB;
      tree_argmax48(sB, bestB, idxB);
      alphaB = (t < LB) ? (bestB + eB[u]) : alphaB;
      // broadcast for next step + backpointer stores (dump rows unread)
      albcA[j] = alphaA;
      albcB[j] = alphaB;
      bp[t * RS + colA] = (unsigned char)idxA;
      bp[t * RS + colB] = (unsigned char)idxB;
      // emit reloads (clamped rows always allocated)
      int r = t + PF; r = r > TT - 1 ? TT - 1 : r;
      eA[u] = lgA[r * DD + jj];
      eB[u] = lgB[r * DD + jj];
    }
  }

  __syncthreads(); // single wave; ordering formality before backtrack

  // final argmax per seq (albc holds final alphas, incl. L==1 via init write)
  float afA[DD], afB[DD];
  {
    const float4* apA = (const float4*)albcA;
    const float4* apB = (const float4*)albcB;
#pragma unroll
    for (int q = 0; q < 12; ++q) {
      float4 a = apA[q];
      afA[4 * q + 0] = a.x; afA[4 * q + 1] = a.y;
      afA[4 * q + 2] = a.z; afA[4 * q + 3] = a.w;
      float4 c = apB[q];
      afB[4 * q + 0] = c.x; afB[4 * q + 1] = c.y;
      afB[4 * q + 2] = c.z; afB[4 * q + 3] = c.w;
    }
  }
  float bvA; int btagA; tree_argmax48(afA, bvA, btagA);
  float bvB; int btagB; tree_argmax48(afB, bvB, btagB);

  int* obA = out + (size_t)(2 * blk) * TT;
  int* obB = out + (size_t)(2 * blk + 1) * TT;
  if (j == 0) {
    obA[LA - 1] = btagA;
    obB[LB - 1] = btagB;
  }

  // interleaved backtracks: H = bp_t[H] via one bpermute per seq per step
  int HA = j, HB = j;
  for (int tt = Lmax - 1; tt >= 1; --tt) {
    if (tt < LA) {
      int vA = bp[tt * RS + jj];
      HA = __shfl(vA, HA, 64);
      if (j == btagA) obA[tt - 1] = HA;
    }
    if (tt < LB) {
      int vB = bp[tt * RS + DD + jj];
      HB = __shfl(vB, HB, 64);
      if (j == btagB) obB[tt - 1] = HB;
    }
  }

  // zero padded tails
  for (int tt = LA + j; tt < TT; tt += 64) obA[tt] = 0;
  for (int tt = LB + j; tt < TT; tt += 64) obB[tt] = 0;
}

extern "C" void kernel_launch(void* const* d_in, const int* in_sizes, int n_in,
                              void* d_out, int out_size, void* d_ws, size_t ws_size,
                              hipStream_t stream) {
  const float* logits = (const float*)d_in[0];
  const int* lens     = (const int*)d_in[1];
  const float* trans  = (const float*)d_in[2];
  int* out            = (int*)d_out;
  (void)in_sizes; (void)n_in; (void)out_size; (void)d_ws; (void)ws_size;
  crf_viterbi<<<256, 64, 0, stream>>>(logits, lens, trans, out);
}

// Round 8
// 314.019 us; speedup vs baseline: 1.5610x; 1.5610x over previous
//
#include <hip/hip_runtime.h>

#define DD 48
#define TT 512
#define BB 512
#define STRIDE 64  // padded LDS row stride for bp
#define PF 4       // emit ring depth == inner unroll (static slots)

__device__ __forceinline__ float readlane_f(float v, int lane) {
  return __int_as_float(__builtin_amdgcn_readlane(__float_as_int(v), lane));
}

// Value: pure fmax/max3 chain (VGPR-only, shallow). Index: cmp/select tree
// strictly off the value path (feeds only the bp store).
// First-index wins ties: move right only on strict (r > l).
__device__ __forceinline__ void tree_argmax48(const float* s, float& best, int& idx) {
  // value tree: 48 -> 16 via max3, then 16 -> 6 -> 2 -> 1
  float m1[16];
#pragma unroll
  for (int k = 0; k < 16; ++k)
    m1[k] = fmaxf(fmaxf(s[3 * k], s[3 * k + 1]), s[3 * k + 2]); // v_max3
  float m2[6];
#pragma unroll
  for (int k = 0; k < 5; ++k)
    m2[k] = fmaxf(fmaxf(m1[3 * k], m1[3 * k + 1]), m1[3 * k + 2]);
  m2[5] = m1[15];
  float m3a = fmaxf(fmaxf(m2[0], m2[1]), m2[2]);
  float m3b = fmaxf(fmaxf(m2[3], m2[4]), m2[5]);
  best = fmaxf(m3a, m3b);

  // index tree (off value path): pairwise first-index-wins
  int x1[24]; float v1[24];
#pragma unroll
  for (int k = 0; k < 24; ++k) {
    float l = s[2 * k], r = s[2 * k + 1];
    v1[k] = fmaxf(l, r);
    x1[k] = (r > l) ? 2 * k + 1 : 2 * k;
  }
  int x2[12]; float v2[12];
#pragma unroll
  for (int k = 0; k < 12; ++k) {
    float l = v1[2 * k], r = v1[2 * k + 1];
    v2[k] = fmaxf(l, r);
    x2[k] = (r > l) ? x1[2 * k + 1] : x1[2 * k];
  }
  int x3[6]; float v3[6];
#pragma unroll
  for (int k = 0; k < 6; ++k) {
    float l = v2[2 * k], r = v2[2 * k + 1];
    v3[k] = fmaxf(l, r);
    x3[k] = (r > l) ? x2[2 * k + 1] : x2[2 * k];
  }
  int x4[3]; float v4[3];
#pragma unroll
  for (int k = 0; k < 3; ++k) {
    float l = v3[2 * k], r = v3[2 * k + 1];
    v4[k] = fmaxf(l, r);
    x4[k] = (r > l) ? x3[2 * k + 1] : x3[2 * k];
  }
  float vm = fmaxf(v4[0], v4[1]);
  int xm = (v4[1] > v4[0]) ? x4[1] : x4[0];
  idx = (v4[2] > vm) ? x4[2] : xm;
}

__global__ __launch_bounds__(64, 1) void crf_viterbi(const float* __restrict__ logits,
                                                     const int* __restrict__ lens,
                                                     const float* __restrict__ trans,
                                                     int* __restrict__ out) {
  const int b = blockIdx.x;
  const int j = threadIdx.x;          // lanes 0..47 are live tags
  const int jj = j < DD ? j : DD - 1; // clamp for safe reads

  __shared__ unsigned char bp[TT * STRIDE]; // 32 KB backpointers

  float tcol[DD];
#pragma unroll
  for (int i = 0; i < DD; ++i) tcol[i] = trans[i * DD + jj];

  const float* lg = logits + (size_t)b * TT * DD;
  const int L = lens[b];

  float alpha = lg[jj]; // alpha0

  // depth-4 emit ring in STATIC slots (no dynamic indexing -> stays in VGPRs)
  float e0, e1, e2, e3;
  {
    int r0 = 1 > TT - 1 ? TT - 1 : 1;
    e0 = lg[r0 * DD + jj];
    e1 = lg[(2 > TT - 1 ? TT - 1 : 2) * DD + jj];
    e2 = lg[(3 > TT - 1 ? TT - 1 : 3) * DD + jj];
    e3 = lg[(4 > TT - 1 ? TT - 1 : 4) * DD + jj];
  }

  // one step: readlane broadcast + adds; value chain fmax-only; index off-path
#define STEP(EV)                                                        \
  {                                                                     \
    float s[DD];                                                        \
    _Pragma("unroll")                                                   \
    for (int i = 0; i < DD; ++i) s[i] = readlane_f(alpha, i) + tcol[i]; \
    float best; int idx;                                                \
    tree_argmax48(s, best, idx);                                        \
    alpha = best + (EV);                                                \
    bp[t * STRIDE + j] = (unsigned char)idx;                            \
  }

#define RELOAD(ES)                                   \
  {                                                  \
    int r = t + PF; r = r > TT - 1 ? TT - 1 : r;     \
    ES = lg[r * DD + jj];                            \
  }

  int t = 1;
  while (t < L) {
    STEP(e0); RELOAD(e0); ++t; if (t >= L) break;
    STEP(e1); RELOAD(e1); ++t; if (t >= L) break;
    STEP(e2); RELOAD(e2); ++t; if (t >= L) break;
    STEP(e3); RELOAD(e3); ++t;
  }
#undef STEP
#undef RELOAD

  __syncthreads(); // single wave; ordering formality before backtrack

  // last_tag = argmax_j alpha (uniform on all lanes)
  float af[DD];
#pragma unroll
  for (int i = 0; i < DD; ++i) af[i] = readlane_f(alpha, i);
  float bv; int btag;
  {
    // reuse index tree for final argmax (value unused)
    tree_argmax48(af, bv, btag);
  }

  int* ob = out + (size_t)b * TT;
  if (j == 0) ob[L - 1] = btag;

  // Backtrack by function composition: H[j] = tag at time t given final tag j.
  int H = j;
  for (int tt = L - 1; tt >= 1; --tt) {
    int v = bp[tt * STRIDE + jj]; // addr independent of H -> pipelined
    H = __shfl(v, H, 64);         // H' = bp_t[H]
    if (j == btag) ob[tt - 1] = H;
  }

  // zero the padded tail t >= L
  for (int tt = L + j; tt < TT; tt += 64) ob[tt] = 0;
}

extern "C" void kernel_launch(void* const* d_in, const int* in_sizes, int n_in,
                              void* d_out, int out_size, void* d_ws, size_t ws_size,
                              hipStream_t stream) {
  const float* logits = (const float*)d_in[0];
  const int* lens     = (const int*)d_in[1];
  const float* trans  = (const float*)d_in[2];
  int* out            = (int*)d_out;
  (void)in_sizes; (void)n_in; (void)out_size; (void)d_ws; (void)ws_size;
  crf_viterbi<<<BB, 64, 0, stream>>>(logits, lens, trans, out);
}